// Round 6
// baseline (4645.703 us; speedup 1.0000x reference)
//
#include <hip/hip_runtime.h>
#include <stdint.h>

// MDLSTM2D: B=16, D0=D1=64, F=U=128, 5 gates (f0,f1,i,o,c)
// ROUND 14 (lockstep discriminator): R13 decomposed the cost: redundant
// weight streaming (655KB/wave/col from L2 = 43GB total) at 10% occupancy.
// R9-R12's residual ~20us/hop gap correlates with a ~95%-IDLE chip (blocks
// 8-deep lookahead, asleep; VALUBusy 7-9%) -> de-boosted clocks + worst-case
// latencies. This round: LOCKSTEP schedule - 8 slices/cell x 16 cols = 512
// tasks/diagonal, grid=512 (2 blocks/CU), so EVERY block works EVERY
// diagonal: proj -> poll(RTT only) -> h-stage -> rec -> signal. Busy ~80%.
// Tight-spin mailbox poll (own line, 1 poller). Bit-identical math (per-col
// k-ascending chains, same expressions). Theory-A (idleness) predicts
// ~1.0-1.3ms; theory-B (fixed 20us hop latency) predicts ~2.7-3.2ms.

typedef float f32x2 __attribute__((ext_vector_type(2)));

#define SCOPE_AGENT __HIP_MEMORY_SCOPE_AGENT

__device__ __forceinline__ float sigm(float x) { return 1.f / (1.f + expf(-x)); }

__global__ void zero_mbox(uint32_t* __restrict__ mbox) {
  // 32768 mailboxes x 64B = 2MB = 524288 u32
  for (int w = blockIdx.x * 256 + threadIdx.x; w < 524288; w += 512 * 256)
    mbox[w] = 0u;
}

__global__ __launch_bounds__(256, 4) void wavefront_kernel(
    const float* __restrict__ x,
    const float* __restrict__ w0, const float* __restrict__ w1, const float* __restrict__ w2,
    const float* __restrict__ w3, const float* __restrict__ w4,
    const float* __restrict__ u0, const float* __restrict__ u1, const float* __restrict__ u2,
    const float* __restrict__ u3, const float* __restrict__ u4,
    const float* __restrict__ bb0, const float* __restrict__ bb1, const float* __restrict__ bb2,
    const float* __restrict__ bb3, const float* __restrict__ bb4,
    float* __restrict__ hbuf, float* __restrict__ cbuf,
    uint32_t* __restrict__ mbox, float* __restrict__ out) {
  __shared__ float xs_hu[16][132];   // x during proj, then h_up during rec
  __shared__ float hl[16][132];
  const int tid = threadIdx.x;
  const int b = tid >> 4;            // batch 0..15
  const int c = tid & 15;            // col-within-slice 0..15
  const int G = gridDim.x;

  int d = 0, base8 = 0, cnt8 = 8;    // cnt8 = 8*cells(d)
  for (int t = blockIdx.x; t < 32768; t += G) {
    while (t >= base8 + cnt8) {
      base8 += cnt8;
      ++d;
      const int lo_ = d > 63 ? d - 63 : 0;
      const int hi_ = d < 63 ? d : 63;
      cnt8 = 8 * (hi_ - lo_ + 1);
    }
    const int r = t - base8;
    const int lo = d > 63 ? d - 63 : 0;
    const int i = lo + (r >> 3);
    const int q = r & 7;
    const int j = d - i;
    const int cell = (i << 6) + j;
    const size_t cb_ = (size_t)cell * 2048;
    const int n = q * 16 + c;        // this thread's single output column

    // ---- 1. stage x[16][128] for this cell ----
    for (int idx = tid; idx < 2048; idx += 256)
      xs_hu[idx >> 7][idx & 127] =
          x[(((size_t)(idx >> 7) * 64 + i) * 64 + j) * 128 + (idx & 127)];
    __syncthreads();

    // ---- 2. projection: this thread's 5 P values (f-ascending, as before) ----
    float p0 = bb0[n], p1 = bb1[n], p2 = bb2[n], p3 = bb3[n], p4 = bb4[n];
    {
      const float* W0 = w0 + n;
      const float* W1 = w1 + n;
      const float* W2 = w2 + n;
      const float* W3 = w3 + n;
      const float* W4 = w4 + n;
#pragma unroll 4
      for (int f = 0; f < 128; ++f) {
        const float xv = xs_hu[b][f];
        p0 += xv * W0[f * 128];
        p1 += xv * W1[f * 128];
        p2 += xv * W2[f * 128];
        p3 += xv * W3[f * 128];
        p4 += xv * W4[f * 128];
      }
    }
    __syncthreads();  // xs fully consumed; buffer reused as h_up below

    // ---- 3. tight-spin on OWN mailbox: 8 signals per existing dep ----
    const int need = 8 * ((i > 0) + (j > 0));
    if (tid == 0 && need) {
      uint32_t* mb = &mbox[(size_t)t * 16];
      while ((int)__hip_atomic_fetch_add(mb, 0u, __ATOMIC_RELAXED, SCOPE_AGENT) < need) {}
    }
    __syncthreads();

    // ---- 4. stage h_up / h_left (full 128-wide vectors) via sc1 loads ----
    for (int idx = tid; idx < 1024; idx += 256) {
      const int bs = idx >> 6, k2 = (idx & 63) << 1;
      unsigned long long vu = 0ull, vl = 0ull;
      if (i > 0)
        vu = __hip_atomic_load(
            (const unsigned long long*)(hbuf + cb_ - 64 * 2048 + bs * 128 + k2),
            __ATOMIC_RELAXED, SCOPE_AGENT);
      if (j > 0)
        vl = __hip_atomic_load(
            (const unsigned long long*)(hbuf + cb_ - 2048 + bs * 128 + k2),
            __ATOMIC_RELAXED, SCOPE_AGENT);
      *(f32x2*)&xs_hu[bs][k2] = __builtin_bit_cast(f32x2, vu);
      *(f32x2*)&hl[bs][k2] = __builtin_bit_cast(f32x2, vl);
    }
    __syncthreads();

    // ---- 5. recurrence: k-ascending scalar chains (order-identical) ----
    float d0 = 0, d1 = 0, d2 = 0, d3 = 0, d4 = 0;
    {
      const float* U0 = u0 + n;
      const float* U1 = u1 + n;
      const float* U2 = u2 + n;
      const float* U3 = u3 + n;
      const float* U4 = u4 + n;
#pragma unroll 8
      for (int k = 0; k < 128; ++k) {
        const float a = xs_hu[b][k], l = hl[b][k], s = a + l;
        d0 += a * U0[k * 128];
        d1 += l * U1[k * 128];
        d2 += s * U2[k * 128];
        d3 += s * U3[k * 128];
        d4 += s * U4[k * 128];
      }
    }

    // ---- 6. gates + state update ----
    const float f0 = sigm(p0 + d0), f1 = sigm(p1 + d1);
    const float it = sigm(p2 + d2), ot = sigm(p3 + d3);
    const float cp = tanhf(p4 + d4);
    float cu = 0.f, cl = 0.f;
    if (i > 0)
      cu = __builtin_bit_cast(float, __hip_atomic_load(
               (const uint32_t*)(cbuf + cb_ - 64 * 2048 + b * 128 + n),
               __ATOMIC_RELAXED, SCOPE_AGENT));
    if (j > 0)
      cl = __builtin_bit_cast(float, __hip_atomic_load(
               (const uint32_t*)(cbuf + cb_ - 2048 + b * 128 + n),
               __ATOMIC_RELAXED, SCOPE_AGENT));
    const float ca = f0 * cu + f1 * cl + it * cp;
    const float ha = ot * tanhf(ca);

    __hip_atomic_store((uint32_t*)(cbuf + cb_ + b * 128 + n),
                       __builtin_bit_cast(uint32_t, ca), __ATOMIC_RELAXED, SCOPE_AGENT);
    __hip_atomic_store((uint32_t*)(hbuf + cb_ + b * 128 + n),
                       __builtin_bit_cast(uint32_t, ha), __ATOMIC_RELAXED, SCOPE_AGENT);
    out[(((size_t)b * 64 + i) * 64 + j) * 128 + n] = ha;

    // ---- 7. publish: barrier drains every wave's vmcnt, then tids 0..15
    // signal the <=16 consumer-slice mailboxes (distinct lines, parallel) ----
    __syncthreads();
    if (d < 126 && tid < 16) {
      const int lo_next = (d + 1) > 63 ? (d + 1) - 63 : 0;
      const int base_next = base8 + cnt8;
      const bool down = tid < 8;     // consumer (i+1,j) vs (i,j+1)
      const int sl = tid & 7;
      if ((down && i < 63) || (!down && j < 63)) {
        const int row = down ? (i + 1) : i;
        const int ct = base_next + 8 * (row - lo_next) + sl;
        __hip_atomic_fetch_add(&mbox[(size_t)ct * 16], 1u, __ATOMIC_RELAXED, SCOPE_AGENT);
      }
    }
  }
}

extern "C" void kernel_launch(void* const* d_in, const int* in_sizes, int n_in,
                              void* d_out, int out_size, void* d_ws, size_t ws_size,
                              hipStream_t stream) {
  const float* x = (const float*)d_in[0];
  const float* w0 = (const float*)d_in[1];
  const float* u0 = (const float*)d_in[2];
  const float* b0 = (const float*)d_in[3];
  const float* w1 = (const float*)d_in[4];
  const float* u1 = (const float*)d_in[5];
  const float* b1 = (const float*)d_in[6];
  const float* w2 = (const float*)d_in[7];
  const float* u2 = (const float*)d_in[8];
  const float* b2 = (const float*)d_in[9];
  const float* w3 = (const float*)d_in[10];
  const float* u3 = (const float*)d_in[11];
  const float* b3 = (const float*)d_in[12];
  const float* w4 = (const float*)d_in[13];
  const float* u4 = (const float*)d_in[14];
  const float* b4 = (const float*)d_in[15];

  char* ws = (char*)d_ws;
  // layout: mbox 32768x64B = 2MB ; hbuf 33.55MB ; cbuf 33.55MB
  const size_t OFF_MBOX = 0;
  const size_t OFF_H = 2097152;
  const size_t OFF_C = OFF_H + (size_t)4096 * 2048 * 4;
  const size_t OFF_END = OFF_C + (size_t)4096 * 2048 * 4;
  if (ws_size < OFF_END) return;

  uint32_t* mbox = (uint32_t*)(ws + OFF_MBOX);
  float* hbuf = (float*)(ws + OFF_H);
  float* cbuf = (float*)(ws + OFF_C);
  float* out = (float*)d_out;

  // grid = 512 (one task per block per diagonal; 2 blocks/CU), multiple of 8
  static int grid = 0;
  if (grid == 0) {
    int dev = 0;
    hipGetDevice(&dev);
    int cus = 0;
    hipDeviceGetAttribute(&cus, hipDeviceAttributeMultiprocessorCount, dev);
    int per_cu = 0;
    hipOccupancyMaxActiveBlocksPerMultiprocessor(&per_cu, (const void*)wavefront_kernel, 256, 0);
    if (cus <= 0) cus = 256;
    if (per_cu <= 0) per_cu = 1;
    long g = (long)cus * (long)per_cu;
    if (g > 512) g = 512;
    g &= ~7L;
    if (g < 8) g = 8;
    grid = (int)g;
  }

  hipLaunchKernelGGL(zero_mbox, dim3(512), dim3(256), 0, stream, mbox);

  void* args[] = {(void*)&x,  (void*)&w0, (void*)&w1, (void*)&w2, (void*)&w3, (void*)&w4,
                  (void*)&u0, (void*)&u1, (void*)&u2, (void*)&u3, (void*)&u4,
                  (void*)&b0, (void*)&b1, (void*)&b2, (void*)&b3, (void*)&b4,
                  (void*)&hbuf, (void*)&cbuf, (void*)&mbox, (void*)&out};
  hipError_t e = hipLaunchCooperativeKernel((const void*)wavefront_kernel, dim3(grid),
                                            dim3(256), args, 0, stream);
  if (e != hipSuccess) {
    (void)hipGetLastError();  // grid <= guaranteed-resident capacity
    wavefront_kernel<<<grid, 256, 0, stream>>>(x, w0, w1, w2, w3, w4, u0, u1, u2, u3, u4,
                                               b0, b1, b2, b3, b4, hbuf, cbuf, mbox, out);
  }
}

// Round 8
// 1565.746 us; speedup vs baseline: 2.9671x; 2.9671x over previous
//
#include <hip/hip_runtime.h>
#include <stdint.h>

// MDLSTM2D: B=16, D0=D1=64, F=U=128, 5 gates (f0,f1,i,o,c)
// ROUND 16: R15 (phase-split + P/out/c aliasing) FAILED correctness - race in
// the new aliasing layer suspected; could not pinpoint by inspection. Retreat
// to R14 (verified, 4645us) + ONE change: W and U slices both LDS-resident
// (80KB weights + 17KB h-bufs = 98.8KB -> 1 block/CU, grid 256, 2 tasks/
// diagonal/block). Theory (stands after R13/R14 accounting): the ~28us/step
// invariant of R9-R14 is the latency-bound weight load chain (1280 global
// loads/thread/step at ~10 outstanding ~= 20-30us). With weights in LDS the
// per-task critical path has ZERO global weight loads. Proj stays fused
// per-task (R14 semantics); all chains f/k-ascending -> bit-identical output.

typedef float f32x2 __attribute__((ext_vector_type(2)));
typedef float f32x4 __attribute__((ext_vector_type(4)));

#define SCOPE_AGENT __HIP_MEMORY_SCOPE_AGENT

__device__ __forceinline__ float sigm(float x) { return 1.f / (1.f + expf(-x)); }

__global__ void zero_mbox(uint32_t* __restrict__ mbox) {
  // 32768 mailboxes x 64B = 2MB = 524288 u32
  for (int w = blockIdx.x * 256 + threadIdx.x; w < 524288; w += 512 * 256)
    mbox[w] = 0u;
}

__global__ __launch_bounds__(256, 1) void wavefront_kernel(
    const float* __restrict__ x,
    const float* __restrict__ w0, const float* __restrict__ w1, const float* __restrict__ w2,
    const float* __restrict__ w3, const float* __restrict__ w4,
    const float* __restrict__ u0, const float* __restrict__ u1, const float* __restrict__ u2,
    const float* __restrict__ u3, const float* __restrict__ u4,
    const float* __restrict__ bb0, const float* __restrict__ bb1, const float* __restrict__ bb2,
    const float* __restrict__ bb3, const float* __restrict__ bb4,
    float* __restrict__ hbuf, float* __restrict__ cbuf,
    uint32_t* __restrict__ mbox, float* __restrict__ out) {
  __shared__ float WL[5][32][16][4];   // 40KB: W n-slice, [g][f>>2][n][f&3]
  __shared__ float UL[5][32][16][4];   // 40KB: U n-slice
  __shared__ float hA[16][132];        // x during proj, h_up during rec
  __shared__ float hB[16][132];        // h_left
  const int tid = threadIdx.x;
  const int b = tid >> 4;              // batch 0..15
  const int c = tid & 15;              // col-within-slice 0..15
  const int G = gridDim.x;             // multiple of 8 -> q fixed per block
  const int q = blockIdx.x & 7;
  const int n = q * 16 + c;            // this thread's output column

  // ---- one-time: load W and U slices into LDS ----
  for (int idx = tid; idx < 10240; idx += 256) {
    const int g = idx >> 11, rem = idx & 2047, f = rem >> 4, nn = rem & 15;
    const float* Wg = g == 0 ? w0 : g == 1 ? w1 : g == 2 ? w2 : g == 3 ? w3 : w4;
    const float* Ug = g == 0 ? u0 : g == 1 ? u1 : g == 2 ? u2 : g == 3 ? u3 : u4;
    WL[g][f >> 2][nn][f & 3] = Wg[f * 128 + q * 16 + nn];
    UL[g][f >> 2][nn][f & 3] = Ug[f * 128 + q * 16 + nn];
  }
  const float bias0 = bb0[n], bias1 = bb1[n], bias2 = bb2[n];
  const float bias3 = bb3[n], bias4 = bb4[n];
  __syncthreads();

  int d = 0, base8 = 0, cnt8 = 8;      // cnt8 = 8*cells(d)
  for (int t = blockIdx.x; t < 32768; t += G) {
    while (t >= base8 + cnt8) {
      base8 += cnt8;
      ++d;
      const int lo_ = d > 63 ? d - 63 : 0;
      const int hi_ = d < 63 ? d : 63;
      cnt8 = 8 * (hi_ - lo_ + 1);
    }
    const int r = t - base8;
    const int lo = d > 63 ? d - 63 : 0;
    const int i = lo + (r >> 3);
    const int j = d - i;
    const int cell = (i << 6) + j;
    const size_t cb_ = (size_t)cell * 2048;

    // ---- 1. stage x[16][128] for this cell ----
    for (int idx = tid; idx < 2048; idx += 256)
      hA[idx >> 7][idx & 127] =
          x[(((size_t)(idx >> 7) * 64 + i) * 64 + j) * 128 + (idx & 127)];
    __syncthreads();

    // ---- 2. projection from LDS (f-ascending per chain, order-identical) ----
    float p0 = bias0, p1 = bias1, p2 = bias2, p3 = bias3, p4 = bias4;
#pragma unroll 4
    for (int f4 = 0; f4 < 32; ++f4) {
      const f32x4 xv = *(const f32x4*)&hA[b][f4 * 4];
      const f32x4 a0 = *(const f32x4*)&WL[0][f4][c][0];
      const f32x4 a1 = *(const f32x4*)&WL[1][f4][c][0];
      const f32x4 a2 = *(const f32x4*)&WL[2][f4][c][0];
      const f32x4 a3 = *(const f32x4*)&WL[3][f4][c][0];
      const f32x4 a4 = *(const f32x4*)&WL[4][f4][c][0];
#pragma unroll
      for (int e = 0; e < 4; ++e) {
        p0 += xv[e] * a0[e]; p1 += xv[e] * a1[e]; p2 += xv[e] * a2[e];
        p3 += xv[e] * a3[e]; p4 += xv[e] * a4[e];
      }
    }
    __syncthreads();                   // xs consumed; hA reused as h_up

    // ---- 3. tight-spin on OWN mailbox: 8 signals per existing dep ----
    const int need = 8 * ((i > 0) + (j > 0));
    if (tid == 0 && need) {
      uint32_t* mb = &mbox[(size_t)t * 16];
      while ((int)__hip_atomic_fetch_add(mb, 0u, __ATOMIC_RELAXED, SCOPE_AGENT) < need) {}
    }
    __syncthreads();

    // ---- 4. stage h_up / h_left via sc1 loads -> LDS; c_u/c_l own cols ----
    for (int idx = tid; idx < 1024; idx += 256) {
      const int bs = idx >> 6, k2 = (idx & 63) << 1;
      unsigned long long vu = 0ull, vl = 0ull;
      if (i > 0)
        vu = __hip_atomic_load(
            (const unsigned long long*)(hbuf + cb_ - 64 * 2048 + bs * 128 + k2),
            __ATOMIC_RELAXED, SCOPE_AGENT);
      if (j > 0)
        vl = __hip_atomic_load(
            (const unsigned long long*)(hbuf + cb_ - 2048 + bs * 128 + k2),
            __ATOMIC_RELAXED, SCOPE_AGENT);
      *(f32x2*)&hA[bs][k2] = __builtin_bit_cast(f32x2, vu);
      *(f32x2*)&hB[bs][k2] = __builtin_bit_cast(f32x2, vl);
    }
    float cu = 0.f, cl = 0.f;
    if (i > 0)
      cu = __builtin_bit_cast(float, __hip_atomic_load(
               (const uint32_t*)(cbuf + cb_ - 64 * 2048 + b * 128 + n),
               __ATOMIC_RELAXED, SCOPE_AGENT));
    if (j > 0)
      cl = __builtin_bit_cast(float, __hip_atomic_load(
               (const uint32_t*)(cbuf + cb_ - 2048 + b * 128 + n),
               __ATOMIC_RELAXED, SCOPE_AGENT));
    __syncthreads();

    // ---- 5. recurrence from LDS (k-ascending chains, order-identical) ----
    float d0 = 0, d1 = 0, d2 = 0, d3 = 0, d4 = 0;
#pragma unroll 4
    for (int k4 = 0; k4 < 32; ++k4) {
      const f32x4 au = *(const f32x4*)&hA[b][k4 * 4];
      const f32x4 al = *(const f32x4*)&hB[b][k4 * 4];
      const f32x4 v0 = *(const f32x4*)&UL[0][k4][c][0];
      const f32x4 v1 = *(const f32x4*)&UL[1][k4][c][0];
      const f32x4 v2 = *(const f32x4*)&UL[2][k4][c][0];
      const f32x4 v3 = *(const f32x4*)&UL[3][k4][c][0];
      const f32x4 v4 = *(const f32x4*)&UL[4][k4][c][0];
#pragma unroll
      for (int e = 0; e < 4; ++e) {
        const float a = au[e], l = al[e], s = a + l;
        d0 += a * v0[e]; d1 += l * v1[e]; d2 += s * v2[e];
        d3 += s * v3[e]; d4 += s * v4[e];
      }
    }

    // ---- 6. gates + state update (identical expressions) ----
    const float f0 = sigm(p0 + d0), f1 = sigm(p1 + d1);
    const float it = sigm(p2 + d2), ot = sigm(p3 + d3);
    const float cp = tanhf(p4 + d4);
    const float ca = f0 * cu + f1 * cl + it * cp;
    const float ha = ot * tanhf(ca);

    __hip_atomic_store((uint32_t*)(cbuf + cb_ + b * 128 + n),
                       __builtin_bit_cast(uint32_t, ca), __ATOMIC_RELAXED, SCOPE_AGENT);
    __hip_atomic_store((uint32_t*)(hbuf + cb_ + b * 128 + n),
                       __builtin_bit_cast(uint32_t, ha), __ATOMIC_RELAXED, SCOPE_AGENT);
    out[(((size_t)b * 64 + i) * 64 + j) * 128 + n] = ha;

    // ---- 7. publish: barrier drains every wave's vmcnt, then tids 0..15
    // signal the <=16 consumer-slice private mailboxes ----
    __syncthreads();
    if (d < 126 && tid < 16) {
      const int lo_next = (d + 1) > 63 ? (d + 1) - 63 : 0;
      const int base_next = base8 + cnt8;
      const bool down = tid < 8;       // consumer (i+1,j) vs (i,j+1)
      const int sl = tid & 7;
      if ((down && i < 63) || (!down && j < 63)) {
        const int row = down ? (i + 1) : i;
        const int ct = base_next + 8 * (row - lo_next) + sl;
        __hip_atomic_fetch_add(&mbox[(size_t)ct * 16], 1u, __ATOMIC_RELAXED, SCOPE_AGENT);
      }
    }
  }
}

extern "C" void kernel_launch(void* const* d_in, const int* in_sizes, int n_in,
                              void* d_out, int out_size, void* d_ws, size_t ws_size,
                              hipStream_t stream) {
  const float* x = (const float*)d_in[0];
  const float* w0 = (const float*)d_in[1];
  const float* u0 = (const float*)d_in[2];
  const float* b0 = (const float*)d_in[3];
  const float* w1 = (const float*)d_in[4];
  const float* u1 = (const float*)d_in[5];
  const float* b1 = (const float*)d_in[6];
  const float* w2 = (const float*)d_in[7];
  const float* u2 = (const float*)d_in[8];
  const float* b2 = (const float*)d_in[9];
  const float* w3 = (const float*)d_in[10];
  const float* u3 = (const float*)d_in[11];
  const float* b3 = (const float*)d_in[12];
  const float* w4 = (const float*)d_in[13];
  const float* u4 = (const float*)d_in[14];
  const float* b4 = (const float*)d_in[15];

  char* ws = (char*)d_ws;
  // layout: mbox 32768x64B = 2MB ; hbuf 33.55MB ; cbuf 33.55MB
  const size_t OFF_MBOX = 0;
  const size_t OFF_H = 2097152;
  const size_t OFF_C = OFF_H + (size_t)4096 * 2048 * 4;
  const size_t OFF_END = OFF_C + (size_t)4096 * 2048 * 4;
  if (ws_size < OFF_END) return;

  uint32_t* mbox = (uint32_t*)(ws + OFF_MBOX);
  float* hbuf = (float*)(ws + OFF_H);
  float* cbuf = (float*)(ws + OFF_C);
  float* out = (float*)d_out;

  // grid: 1 block/CU at 98.8KB LDS -> 256; multiple of 8 keeps q fixed
  static int grid = 0;
  if (grid == 0) {
    int dev = 0;
    hipGetDevice(&dev);
    int cus = 0;
    hipDeviceGetAttribute(&cus, hipDeviceAttributeMultiprocessorCount, dev);
    int per_cu = 0;
    hipOccupancyMaxActiveBlocksPerMultiprocessor(&per_cu, (const void*)wavefront_kernel, 256, 0);
    if (cus <= 0) cus = 256;
    if (per_cu <= 0) per_cu = 1;
    long g = (long)cus * (long)per_cu;
    if (g > 512) g = 512;
    g &= ~7L;
    if (g < 8) g = 8;
    grid = (int)g;
  }

  hipLaunchKernelGGL(zero_mbox, dim3(512), dim3(256), 0, stream, mbox);

  void* args[] = {(void*)&x,  (void*)&w0, (void*)&w1, (void*)&w2, (void*)&w3, (void*)&w4,
                  (void*)&u0, (void*)&u1, (void*)&u2, (void*)&u3, (void*)&u4,
                  (void*)&b0, (void*)&b1, (void*)&b2, (void*)&b3, (void*)&b4,
                  (void*)&hbuf, (void*)&cbuf, (void*)&mbox, (void*)&out};
  hipError_t e = hipLaunchCooperativeKernel((const void*)wavefront_kernel, dim3(grid),
                                            dim3(256), args, 0, stream);
  if (e != hipSuccess) {
    (void)hipGetLastError();  // grid <= guaranteed-resident capacity
    wavefront_kernel<<<grid, 256, 0, stream>>>(x, w0, w1, w2, w3, w4, u0, u1, u2, u3, u4,
                                               b0, b1, b2, b3, b4, hbuf, cbuf, mbox, out);
  }
}